// Round 2
// baseline (569.455 us; speedup 1.0000x reference)
//
#include <hip/hip_runtime.h>

// Block-circulant matmul via FFT, round 2: 16x16 four-step FFT.
//   FFT_256 = DFT16(n2) -> twiddle W256^(n1*k2) -> DFT16(n1), DFT16 in registers.
// One 512-thread block handles TWO batch rows (amortizes Wc L2 traffic).
// Within a row, FFT jj is owned by 16 contiguous threads -> whole FFT is
// wave-private -> no barriers inside FFT (same-wave DS ops are in-order).
// LDS layouts (region stride R=264 floats, +8 pad => jj adds 8 banks/region):
//   x / Y / output: natural   addr = R*jj + n1 + 16*n2          (<=2-way)
//   G (transpose):  skewed    addr = R*jj + 16*k2 + ((n1+k2)&15) (<=2-way)
//   load/store phases: float4 <-> ds_*_b128 at 16B lane stride   (conflict-free)

#define TWO_PI 6.283185307179586f

constexpr int R = 264;   // floats per FFT region (256 + 8 pad)

// 16-point complex DFT in registers, Stockham radix-4 x radix-4, natural order.
// VS=+1: forward (e^{-i}); VS=-1: inverse (e^{+i}, unnormalized).
template<int VS>
__device__ __forceinline__ void fft16(float* re, float* im)
{
    const float C16[10] = {1.f, 0.92387953f, 0.70710678f, 0.38268343f, 0.f,
                           -0.38268343f, -0.70710678f, -0.92387953f, -1.f, -0.92387953f};
    const float S16[10] = {0.f, 0.38268343f, 0.70710678f, 0.92387953f, 1.f,
                           0.92387953f, 0.70710678f, 0.38268343f, 0.f, -0.38268343f};
    float sr[16], si[16];
#pragma unroll
    for (int w = 0; w < 4; ++w) {
        float t0r = re[w] + re[w + 8],      t0i = im[w] + im[w + 8];
        float t1r = re[w] - re[w + 8],      t1i = im[w] - im[w + 8];
        float t2r = re[w + 4] + re[w + 12], t2i = im[w + 4] + im[w + 12];
        float t3r = re[w + 4] - re[w + 12], t3i = im[w + 4] - im[w + 12];
        float b0r = t0r + t2r, b0i = t0i + t2i;
        float b2r = t0r - t2r, b2i = t0i - t2i;
        float b1r = t1r + VS * t3i, b1i = t1i - VS * t3r;
        float b3r = t1r - VS * t3i, b3i = t1i + VS * t3r;
        sr[4 * w]     = b0r;                                si[4 * w]     = b0i;
        sr[4 * w + 1] = b1r * C16[w]     + VS * b1i * S16[w];     si[4 * w + 1] = b1i * C16[w]     - VS * b1r * S16[w];
        sr[4 * w + 2] = b2r * C16[2 * w] + VS * b2i * S16[2 * w]; si[4 * w + 2] = b2i * C16[2 * w] - VS * b2r * S16[2 * w];
        sr[4 * w + 3] = b3r * C16[3 * w] + VS * b3i * S16[3 * w]; si[4 * w + 3] = b3i * C16[3 * w] - VS * b3r * S16[3 * w];
    }
#pragma unroll
    for (int q = 0; q < 4; ++q) {
        float t0r = sr[q] + sr[q + 8],      t0i = si[q] + si[q + 8];
        float t1r = sr[q] - sr[q + 8],      t1i = si[q] - si[q + 8];
        float t2r = sr[q + 4] + sr[q + 12], t2i = si[q + 4] + si[q + 12];
        float t3r = sr[q + 4] - sr[q + 12], t3i = si[q + 4] - si[q + 12];
        re[q]      = t0r + t2r;          im[q]      = t0i + t2i;
        re[q + 8]  = t0r - t2r;          im[q + 8]  = t0i - t2i;
        re[q + 4]  = t1r + VS * t3i;     im[q + 4]  = t1i - VS * t3r;
        re[q + 12] = t1r - VS * t3i;     im[q + 12] = t1i + VS * t3r;
    }
}

// Full 256-pt FFT on region `base` of (ar, ai); thread role u16 in [0,16).
// Wave-private: the 16 threads of a region live in one wave -> no barrier.
template<int VS>
__device__ __forceinline__ void fft256(float* ar, float* ai, int base, int u16)
{
    float er[16], ei[16];
    // step 1: DFT over n2 of x[n1 + 16 n2], n1 = u16 (reads natural layout)
    int n1 = u16;
#pragma unroll
    for (int n2 = 0; n2 < 16; ++n2) {
        er[n2] = ar[base + n1 + 16 * n2];
        ei[n2] = ai[base + n1 + 16 * n2];
    }
    fft16<VS>(er, ei);
    // twiddle W256^{n1*k2} (conjugated for inverse), iterative complex mul
    float sb, cb;
    __sincosf(TWO_PI * (float)n1 * (1.0f / 256.0f), &sb, &cb);
    sb = -VS * sb;
    float twr = 1.f, twi = 0.f;
#pragma unroll
    for (int k2 = 0; k2 < 16; ++k2) {
        float gr = er[k2] * twr - ei[k2] * twi;
        float gi = er[k2] * twi + ei[k2] * twr;
        int a = base + 16 * k2 + ((n1 + k2) & 15);   // skewed G layout
        ar[a] = gr;
        ai[a] = gi;
        float ntr = twr * cb - twi * sb;
        twi = twr * sb + twi * cb;
        twr = ntr;
    }
    // step 2: DFT over n1 of G[n1][k2], k2 = u16 (reads skewed layout)
    int k2 = u16;
#pragma unroll
    for (int m = 0; m < 16; ++m) {
        int a = base + 16 * k2 + ((m + k2) & 15);
        er[m] = ar[a];
        ei[m] = ai[a];
    }
    fft16<VS>(er, ei);
    // write X[k2 + 16 k1] to natural layout
#pragma unroll
    for (int k1 = 0; k1 < 16; ++k1) {
        ar[base + k2 + 16 * k1] = er[k1];
        ai[base + k2 + 16 * k1] = ei[k1];
    }
}

// Wc[f][i][j] = conj(FFT(W[i,j,:]))[f], f = 0..128, into d_ws.
__global__ __launch_bounds__(256) void wfft_kernel(const float* __restrict__ W,
                                                   float2* __restrict__ Wc)
{
    __shared__ float wblk[256];
    __shared__ float tabr[256], tabi[256];
    int t   = threadIdx.x;
    int blk = blockIdx.x;          // blk = i*16 + j
    wblk[t] = W[blk * 256 + t];
    float s, c;
    __sincosf((float)t * (TWO_PI / 256.0f), &s, &c);
    tabr[t] = c; tabi[t] = s;
    __syncthreads();
    if (t < 129) {
        float ar = 0.f, ai = 0.f;
        for (int cc = 0; cc < 256; ++cc) {
            int idx = (t * cc) & 255;
            float wv = wblk[cc];
            ar = fmaf(wv, tabr[idx], ar);
            ai = fmaf(wv, tabi[idx], ai);
        }
        int i = blk >> 4, j = blk & 15;
        Wc[(t * 16 + i) * 16 + j] = make_float2(ar, ai);
    }
}

__global__ __launch_bounds__(512) void bc_kernel(const float* __restrict__ x,
                                                 const float* __restrict__ d,
                                                 const float* __restrict__ bias,
                                                 const float2* __restrict__ Wc,
                                                 float* __restrict__ out)
{
    __shared__ float Ar[2][16 * R], Ai[2][16 * R];
    int t  = threadIdx.x;
    int r  = t >> 8;               // which of the 2 rows this thread serves
    int tt = t & 255;
    int row_g = blockIdx.x * 2 + r;
    float* ar = Ar[r];
    float* ai = Ai[r];
    int jj   = tt >> 4;            // FFT region 0..15
    int u16  = tt & 15;            // role within region
    int base = jj * R;

    // ---- load: coalesced float4, ds_write_b128 (16B lane stride, no conflict)
    const float4* x4 = (const float4*)(x + (size_t)row_g * 4096);
    const float4* d4 = (const float4*)d;
#pragma unroll
    for (int u = 0; u < 4; ++u) {
        int idx = u * 256 + tt;
        float4 xv = x4[idx], dv = d4[idx];
        int a0 = (idx >> 6) * R + (idx & 63) * 4;
        float4 v;
        v.x = xv.x * dv.x; v.y = xv.y * dv.y; v.z = xv.z * dv.z; v.w = xv.w * dv.w;
        *(float4*)(ar + a0) = v;
        *(float4*)(ai + a0) = make_float4(0.f, 0.f, 0.f, 0.f);
    }
    __syncthreads();                                   // BAR 1

    fft256<1>(ar, ai, base, u16);                      // forward, no barriers
    __syncthreads();                                   // BAR 2

    // ---- frequency-domain matmul: 2 threads per f (i split 0..7 / 8..15)
    int f  = (tt <= 128) ? tt : (tt - 128);
    int i0 = (tt <= 128) ? 0 : 8;
    float xr[16], xi[16];
#pragma unroll
    for (int j = 0; j < 16; ++j) {
        xr[j] = ar[j * R + f];
        xi[j] = ai[j * R + f];
    }
    __syncthreads();                                   // BAR 3 (all reads before writes)

#pragma unroll 1
    for (int pass = 0; pass < 2; ++pass) {
        if (pass == 1 && !(tt == 0 || tt == 128)) break;  // extras: f=0,128 need i 8..15
        int ib = (pass == 0) ? i0 : 8;
#pragma unroll
        for (int io = 0; io < 8; ++io) {
            int i = ib + io;
            const float4* wv4 = (const float4*)(Wc + ((size_t)f * 16 + i) * 16);
            float yr = 0.f, yi = 0.f;
#pragma unroll
            for (int j2 = 0; j2 < 8; ++j2) {
                float4 wv = wv4[j2];
                int j0 = 2 * j2;
                yr = fmaf(xr[j0], wv.x, yr); yr = fmaf(-xi[j0], wv.y, yr);
                yi = fmaf(xr[j0], wv.y, yi); yi = fmaf(xi[j0], wv.x, yi);
                yr = fmaf(xr[j0 + 1], wv.z, yr); yr = fmaf(-xi[j0 + 1], wv.w, yr);
                yi = fmaf(xr[j0 + 1], wv.w, yi); yi = fmaf(xi[j0 + 1], wv.z, yi);
            }
            ar[i * R + f] = yr;                         // natural layout (ifft input)
            ai[i * R + f] = yi;
            if (f >= 1 && f <= 127) {                   // conjugate symmetry
                ar[i * R + 256 - f] = yr;
                ai[i * R + 256 - f] = -yi;
            }
        }
    }
    __syncthreads();                                   // BAR 4

    fft256<-1>(ar, ai, base, u16);                     // inverse, no barriers
    __syncthreads();                                   // BAR 5

    // ---- store: ds_read_b128 + coalesced float4, scale 1/256 + bias
    const float4* b4 = (const float4*)bias;
    float* op = out + (size_t)row_g * 4096;
#pragma unroll
    for (int u = 0; u < 4; ++u) {
        int idx = u * 256 + tt;
        int a0 = (idx >> 6) * R + (idx & 63) * 4;
        float4 v  = *(const float4*)(ar + a0);
        float4 bv = b4[idx];
        float4 ov;
        ov.x = v.x * (1.f / 256.f) + bv.x;
        ov.y = v.y * (1.f / 256.f) + bv.y;
        ov.z = v.z * (1.f / 256.f) + bv.z;
        ov.w = v.w * (1.f / 256.f) + bv.w;
        ((float4*)op)[idx] = ov;
    }
}

extern "C" void kernel_launch(void* const* d_in, const int* in_sizes, int n_in,
                              void* d_out, int out_size, void* d_ws, size_t ws_size,
                              hipStream_t stream)
{
    const float* x    = (const float*)d_in[0];   // (8192, 4096)
    const float* W    = (const float*)d_in[1];   // (16, 16, 256)
    const float* d    = (const float*)d_in[2];   // (4096,)
    const float* bias = (const float*)d_in[3];   // (4096,)
    float* out = (float*)d_out;
    float2* Wc = (float2*)d_ws;                  // [129][16][16] complex

    wfft_kernel<<<256, 256, 0, stream>>>(W, Wc);
    bc_kernel<<<4096, 512, 0, stream>>>(x, d, bias, Wc, out);
}

// Round 3
// 497.272 us; speedup vs baseline: 1.1452x; 1.1452x over previous
//
#include <hip/hip_runtime.h>

// Block-circulant matmul via FFT, round 3: in-place DIF/DIT radix-4.
//   fwd DIF (natural -> base4-digit-reversed), per-position 16x16 complex
//   matmul against a position-permuted Wc table, inv DIT (reversed -> natural).
// One row per 256-thread block, single LDS buffer pair (38 KiB -> 4 blocks/CU).
// Swizzle phys(a) = a + 4*(a>>5) keeps every LDS pattern <= 2-way (free).
// Wc table: Wc2[i][jc][pos] float4, 512 KB, L2-resident, coalesced reads.

#define TWO_PI 6.283185307179586f

constexpr int RS = 288;                 // region stride in floats (256 + swizzle pad)

__device__ __forceinline__ int phys(int a) { return a + ((a >> 5) << 2); }

__device__ __forceinline__ int rev4(int p) {
    return ((p & 3) << 6) | (((p >> 2) & 3) << 4) | (((p >> 4) & 3) << 2) | ((p >> 6) & 3);
}

// One in-place radix-4 stage over 16 regions. D = butterfly distance.
// FWD: DIF (butterfly then twiddle W256^{-s*M*n}); else DIT inverse
// (twiddle W256^{+s*M*n} then +i butterfly). M = 64/D. 4 independent
// butterflies per thread; no intra-stage hazards (each owns its 4 slots).
template<int D, bool FWD>
__device__ __forceinline__ void stage(float* __restrict__ Ar, float* __restrict__ Ai,
                                      const float* __restrict__ tabc, const float* __restrict__ tabs,
                                      int tt)
{
    constexpr int M = 64 / D;
#pragma unroll
    for (int r = 0; r < 4; ++r) {
        int reg  = (r * 256 + tt) >> 6;     // one region per (wave, r)
        int w    = tt & 63;
        int g    = w / D;
        int n    = w % D;
        int base = reg * RS;
        int a0   = g * 4 * D + n;
        int i0 = base + phys(a0);
        int i1 = base + phys(a0 + D);
        int i2 = base + phys(a0 + 2 * D);
        int i3 = base + phys(a0 + 3 * D);
        float ar = Ar[i0], aj = Ai[i0];
        float br = Ar[i1], bj = Ai[i1];
        float cr = Ar[i2], cj = Ai[i2];
        float er = Ar[i3], ej = Ai[i3];
        if (FWD) {
            float t0r = ar + cr, t0i = aj + cj, t1r = ar - cr, t1i = aj - cj;
            float t2r = br + er, t2i = bj + ej, t3r = br - er, t3i = bj - ej;
            float u0r = t0r + t2r, u0i = t0i + t2i;
            float u1r = t1r + t3i, u1i = t1i - t3r;   // t1 - i*t3
            float u2r = t0r - t2r, u2i = t0i - t2i;
            float u3r = t1r - t3i, u3i = t1i + t3r;   // t1 + i*t3
            Ar[i0] = u0r; Ai[i0] = u0i;
            if (D == 1) {
                Ar[i1] = u1r; Ai[i1] = u1i;
                Ar[i2] = u2r; Ai[i2] = u2i;
                Ar[i3] = u3r; Ai[i3] = u3i;
            } else {
                int x1 = (M * n) & 255, x2 = (2 * M * n) & 255, x3 = (3 * M * n) & 255;
                float c1 = tabc[x1], s1 = tabs[x1];
                float c2 = tabc[x2], s2 = tabs[x2];
                float c3 = tabc[x3], s3 = tabs[x3];
                Ar[i1] = u1r * c1 + u1i * s1;  Ai[i1] = u1i * c1 - u1r * s1;  // *(c - i s)
                Ar[i2] = u2r * c2 + u2i * s2;  Ai[i2] = u2i * c2 - u2r * s2;
                Ar[i3] = u3r * c3 + u3i * s3;  Ai[i3] = u3i * c3 - u3r * s3;
            }
        } else {
            float v1r, v1i, v2r, v2i, v3r, v3i;
            if (D == 1) {
                v1r = br; v1i = bj; v2r = cr; v2i = cj; v3r = er; v3i = ej;
            } else {
                int x1 = (M * n) & 255, x2 = (2 * M * n) & 255, x3 = (3 * M * n) & 255;
                float c1 = tabc[x1], s1 = tabs[x1];
                float c2 = tabc[x2], s2 = tabs[x2];
                float c3 = tabc[x3], s3 = tabs[x3];
                v1r = br * c1 - bj * s1;  v1i = br * s1 + bj * c1;            // *(c + i s)
                v2r = cr * c2 - cj * s2;  v2i = cr * s2 + cj * c2;
                v3r = er * c3 - ej * s3;  v3i = er * s3 + ej * c3;
            }
            float t0r = ar + v2r,  t0i = aj + v2i,  t1r = ar - v2r,  t1i = aj - v2i;
            float t2r = v1r + v3r, t2i = v1i + v3i, t3r = v1r - v3r, t3i = v1i - v3i;
            Ar[i0] = t0r + t2r;  Ai[i0] = t0i + t2i;
            Ar[i1] = t1r - t3i;  Ai[i1] = t1i + t3r;   // t1 + i*t3
            Ar[i2] = t0r - t2r;  Ai[i2] = t0i - t2i;
            Ar[i3] = t1r + t3i;  Ai[i3] = t1i - t3r;   // t1 - i*t3
        }
    }
}

// Wc2[i][jc][pos] float4 = (Hc[f][i][2jc].re,.im, Hc[f][i][2jc+1].re,.im),
// pos = rev4(f), Hc[f][i][j] = conj(FFT_256(W[i,j,:]))[f] = sum_c W*e^{+2pi i fc/256}.
// All 256 f computed directly (covers f>128 without conj bookkeeping).
__global__ __launch_bounds__(256) void wfft_kernel(const float* __restrict__ W,
                                                   float* __restrict__ Wc2)
{
    __shared__ float wblk[256];
    __shared__ float tabc[256], tabs[256];
    int t   = threadIdx.x;                 // t = frequency f
    int blk = blockIdx.x;                  // blk = i*16 + j
    wblk[t] = W[blk * 256 + t];
    float s, c;
    __sincosf((float)t * (TWO_PI / 256.0f), &s, &c);
    tabc[t] = c; tabs[t] = s;
    __syncthreads();
    float ar = 0.f, ai = 0.f;
    for (int cc = 0; cc < 256; ++cc) {
        int idx = (t * cc) & 255;
        float wv = wblk[cc];
        ar = fmaf(wv, tabc[idx], ar);
        ai = fmaf(wv, tabs[idx], ai);
    }
    int i = blk >> 4, j = blk & 15;
    int p = rev4(t);
    int flat = ((i * 8 + (j >> 1)) * 256 + p) * 4 + (j & 1) * 2;
    Wc2[flat]     = ar;
    Wc2[flat + 1] = ai;
}

__global__ __launch_bounds__(256) void bc_kernel(const float* __restrict__ x,
                                                 const float* __restrict__ d,
                                                 const float* __restrict__ bias,
                                                 const float* __restrict__ Wc2,
                                                 float* __restrict__ out)
{
    __shared__ float Ar[16 * RS], Ai[16 * RS];
    __shared__ float tabc[256], tabs[256];
    int t = threadIdx.x;
    int b = blockIdx.x;

    float sv, cv;
    __sincosf((float)t * (TWO_PI / 256.0f), &sv, &cv);
    tabc[t] = cv; tabs[t] = sv;

    // ---- load row, fold d (+/-1). float4 global, swizzled float4 LDS writes.
    const float4* x4 = (const float4*)(x + (size_t)b * 4096);
    const float4* d4 = (const float4*)d;
#pragma unroll
    for (int u = 0; u < 4; ++u) {
        int idx = u * 256 + t;            // float4 index 0..1023
        float4 xv = x4[idx], dv = d4[idx];
        int m  = idx & 63;                // float4 within region
        int a0 = (idx >> 6) * RS + 4 * m + ((m >> 3) << 2);   // phys(4m)+region
        float4 v;
        v.x = xv.x * dv.x; v.y = xv.y * dv.y; v.z = xv.z * dv.z; v.w = xv.w * dv.w;
        *(float4*)(Ar + a0) = v;
        *(float4*)(Ai + a0) = make_float4(0.f, 0.f, 0.f, 0.f);
    }
    __syncthreads();

    // ---- forward DIF: D = 64, 16, 4, 1
    stage<64, true>(Ar, Ai, tabc, tabs, t); __syncthreads();
    stage<16, true>(Ar, Ai, tabc, tabs, t); __syncthreads();
    stage< 4, true>(Ar, Ai, tabc, tabs, t); __syncthreads();
    stage< 1, true>(Ar, Ai, tabc, tabs, t); __syncthreads();

    // ---- per-position 16x16 complex matmul; thread t owns position t.
    // Column-private in-place update: read all j, then write all i.
    {
        int pq = phys(t);
        float xr[16], xi[16];
#pragma unroll
        for (int j = 0; j < 16; ++j) {
            xr[j] = Ar[j * RS + pq];
            xi[j] = Ai[j * RS + pq];
        }
        const float4* wp = (const float4*)Wc2 + t;   // + (i*8+jc)*256
#pragma unroll 2
        for (int i = 0; i < 16; ++i) {
            float yr = 0.f, yi = 0.f;
#pragma unroll
            for (int jc = 0; jc < 8; ++jc) {
                float4 wv = wp[(i * 8 + jc) * 256];
                int j0 = 2 * jc;
                yr = fmaf(xr[j0], wv.x, yr); yr = fmaf(-xi[j0], wv.y, yr);
                yi = fmaf(xr[j0], wv.y, yi); yi = fmaf(xi[j0], wv.x, yi);
                yr = fmaf(xr[j0 + 1], wv.z, yr); yr = fmaf(-xi[j0 + 1], wv.w, yr);
                yi = fmaf(xr[j0 + 1], wv.w, yi); yi = fmaf(xi[j0 + 1], wv.z, yi);
            }
            Ar[i * RS + pq] = yr;
            Ai[i * RS + pq] = yi;
        }
    }
    __syncthreads();

    // ---- inverse DIT: D = 1, 4, 16, 64 (consumes digit-reversed, emits natural)
    stage< 1, false>(Ar, Ai, tabc, tabs, t); __syncthreads();
    stage< 4, false>(Ar, Ai, tabc, tabs, t); __syncthreads();
    stage<16, false>(Ar, Ai, tabc, tabs, t); __syncthreads();
    stage<64, false>(Ar, Ai, tabc, tabs, t); __syncthreads();

    // ---- store real/256 + bias
    const float4* b4 = (const float4*)bias;
    float* op = out + (size_t)b * 4096;
#pragma unroll
    for (int u = 0; u < 4; ++u) {
        int idx = u * 256 + t;
        int m   = idx & 63;
        int a0  = (idx >> 6) * RS + 4 * m + ((m >> 3) << 2);
        float4 v  = *(const float4*)(Ar + a0);
        float4 bv = b4[idx];
        float4 ov;
        ov.x = v.x * (1.f / 256.f) + bv.x;
        ov.y = v.y * (1.f / 256.f) + bv.y;
        ov.z = v.z * (1.f / 256.f) + bv.z;
        ov.w = v.w * (1.f / 256.f) + bv.w;
        ((float4*)op)[idx] = ov;
    }
}

extern "C" void kernel_launch(void* const* d_in, const int* in_sizes, int n_in,
                              void* d_out, int out_size, void* d_ws, size_t ws_size,
                              hipStream_t stream)
{
    const float* x    = (const float*)d_in[0];   // (8192, 4096)
    const float* W    = (const float*)d_in[1];   // (16, 16, 256)
    const float* d    = (const float*)d_in[2];   // (4096,)
    const float* bias = (const float*)d_in[3];   // (4096,)
    float* out = (float*)d_out;
    float* Wc2 = (float*)d_ws;                   // [16][8][256] float4 = 512 KB

    wfft_kernel<<<256, 256, 0, stream>>>(W, Wc2);
    bc_kernel<<<8192, 256, 0, stream>>>(x, d, bias, Wc2, out);
}

// Round 4
// 328.885 us; speedup vs baseline: 1.7315x; 1.5120x over previous
//
#include <hip/hip_runtime.h>

// Block-circulant matmul via FFT, round 4: fused radix-16 pairs.
// FFT-256 done as two register-resident "pairs" (each = 2 radix-4 DIF stages),
// so a full FFT costs 2 LDS round trips. All twiddles computed in registers
// (one __sincosf + angle addition) - no LDS twiddle tables.
// Forward DIF emits digit-reversed; pair-2's scatter write applies rev4 so the
// spectrum lands in NATURAL order -> round-2's proven conj-symmetric matmul.
// Inverse = same DIF with conjugate twiddles (natural in, digit-reversed out);
// the final global-store gather applies rev4.
// Wave-owned regions: each wave loads + FFTs only its own 4 FFT regions, so
// load->fft->scatter and ifft->store need NO barriers (same-wave DS ordering).
// Only 3 barriers/block (around the cross-wave frequency matmul).
// LDS: Ar/Ai [16*304] floats = 38 KiB; phys() swizzle keeps b32 phases <=2-way.

#define TWO_PI 6.283185307179586f
constexpr int RS = 304;   // region stride (mod 32 == 16 -> 2-way across regions)

__device__ __forceinline__ int phys(int a) { return a + ((a >> 5) << 2); }

// (vr,vi) *= e^{-i*SGN*alpha}, where (c,s) = (cos alpha, sin alpha)
template<int SGN>
__device__ __forceinline__ void twmul(float& vr, float& vi, float c, float s)
{
    float r = vr * c + SGN * (vi * s);
    float i = vi * c - SGN * (vr * s);
    vr = r; vi = i;
}

// Pair 1 = DIF stages D=64 (butterfly over k, twiddle angle (th+pi*m/8)*r)
// and D=16 (butterfly over m, twiddle angle 4*th*r), th = 2*pi*u/256.
// Elements: position u + 16m + 64k <-> register s = m + 4k.
template<int SGN, bool REAL>
__device__ __forceinline__ void pair1(float* __restrict__ Ar, float* __restrict__ Ai,
                                      int base, int u)
{
    float xr[16], xi[16];
#pragma unroll
    for (int s = 0; s < 16; ++s) {
        int a = base + phys(u + 16 * s);
        xr[s] = Ar[a];
        if (!REAL) xi[s] = Ai[a];
    }
    float su, cu;
    __sincosf((float)u * (TWO_PI / 256.f), &su, &cu);
    const float CM[4] = {1.f, 0.92387953f, 0.70710678f, 0.38268343f};
    const float SM[4] = {0.f, 0.38268343f, 0.70710678f, 0.92387953f};
    float c1[4], s1[4], c2[4], s2[4], c3[4], s3[4];
#pragma unroll
    for (int m = 0; m < 4; ++m) {
        c1[m] = cu * CM[m] - su * SM[m];
        s1[m] = su * CM[m] + cu * SM[m];
        c2[m] = c1[m] * c1[m] - s1[m] * s1[m];
        s2[m] = 2.f * c1[m] * s1[m];
        c3[m] = c2[m] * c1[m] - s2[m] * s1[m];
        s3[m] = s2[m] * c1[m] + c2[m] * s1[m];
    }
    // stage A (D=64): A_k = x[m+4k]
#pragma unroll
    for (int m = 0; m < 4; ++m) {
        if (REAL) {
            float a0 = xr[m], a1 = xr[m + 4], a2 = xr[m + 8], a3 = xr[m + 12];
            float t0 = a0 + a2, t1 = a0 - a2, t2 = a1 + a3, t3 = a1 - a3;
            xr[m] = t0 + t2;  xi[m] = 0.f;
            xr[m + 4]  = t1 * c1[m] - t3 * s1[m];
            xi[m + 4]  = -SGN * (t3 * c1[m] + t1 * s1[m]);
            float dd   = t0 - t2;
            xr[m + 8]  = dd * c2[m];
            xi[m + 8]  = -SGN * (dd * s2[m]);
            xr[m + 12] = t1 * c3[m] + t3 * s3[m];
            xi[m + 12] = SGN * (t3 * c3[m] - t1 * s3[m]);
        } else {
            float t0r = xr[m] + xr[m + 8],       t0i = xi[m] + xi[m + 8];
            float t1r = xr[m] - xr[m + 8],       t1i = xi[m] - xi[m + 8];
            float t2r = xr[m + 4] + xr[m + 12],  t2i = xi[m + 4] + xi[m + 12];
            float t3r = xr[m + 4] - xr[m + 12],  t3i = xi[m + 4] - xi[m + 12];
            xr[m] = t0r + t2r;  xi[m] = t0i + t2i;
            float v1r = t1r + SGN * t3i, v1i = t1i - SGN * t3r;
            float v2r = t0r - t2r,       v2i = t0i - t2i;
            float v3r = t1r - SGN * t3i, v3i = t1i + SGN * t3r;
            twmul<SGN>(v1r, v1i, c1[m], s1[m]);
            twmul<SGN>(v2r, v2i, c2[m], s2[m]);
            twmul<SGN>(v3r, v3i, c3[m], s3[m]);
            xr[m + 4]  = v1r; xi[m + 4]  = v1i;
            xr[m + 8]  = v2r; xi[m + 8]  = v2i;
            xr[m + 12] = v3r; xi[m + 12] = v3i;
        }
    }
    // stage B (D=16): A_m = x[4k+m], twiddle angles 4th, 8th, 12th
    float cb1 = cu * cu - su * su, sb1 = 2.f * cu * su;            // 2th
    { float c = cb1, s = sb1; cb1 = c * c - s * s; sb1 = 2.f * c * s; }  // 4th
    float cb2 = cb1 * cb1 - sb1 * sb1, sb2 = 2.f * cb1 * sb1;      // 8th
    float cb3 = cb2 * cb1 - sb2 * sb1, sb3 = sb2 * cb1 + cb2 * sb1; // 12th
#pragma unroll
    for (int k = 0; k < 4; ++k) {
        int s0 = 4 * k;
        float t0r = xr[s0] + xr[s0 + 2],     t0i = xi[s0] + xi[s0 + 2];
        float t1r = xr[s0] - xr[s0 + 2],     t1i = xi[s0] - xi[s0 + 2];
        float t2r = xr[s0 + 1] + xr[s0 + 3], t2i = xi[s0 + 1] + xi[s0 + 3];
        float t3r = xr[s0 + 1] - xr[s0 + 3], t3i = xi[s0 + 1] - xi[s0 + 3];
        xr[s0] = t0r + t2r;  xi[s0] = t0i + t2i;
        float v1r = t1r + SGN * t3i, v1i = t1i - SGN * t3r;
        float v2r = t0r - t2r,       v2i = t0i - t2i;
        float v3r = t1r - SGN * t3i, v3i = t1i + SGN * t3r;
        twmul<SGN>(v1r, v1i, cb1, sb1);
        twmul<SGN>(v2r, v2i, cb2, sb2);
        twmul<SGN>(v3r, v3i, cb3, sb3);
        xr[s0 + 1] = v1r; xi[s0 + 1] = v1i;
        xr[s0 + 2] = v2r; xi[s0 + 2] = v2i;
        xr[s0 + 3] = v3r; xi[s0 + 3] = v3i;
    }
#pragma unroll
    for (int s = 0; s < 16; ++s) {
        int a = base + phys(u + 16 * s);
        Ar[a] = xr[s]; Ai[a] = xi[s];
    }
}

// Pair 2 = DIF stages D=4 (butterfly over m, s=q+4m, twiddle angle pi*q*r/8,
// compile-time) and D=1 (butterfly over contiguous quad, no twiddle).
// Elements: position 16u + s (contiguous -> float4 LDS I/O).
// STORE_REV: scatter outputs to rev4(position) (natural-order spectrum).
// REAL_OUT: final inverse pair - compute/store real part only, contiguous.
template<int SGN, bool STORE_REV, bool REAL_OUT>
__device__ __forceinline__ void pair2(float* __restrict__ Ar, float* __restrict__ Ai,
                                      int base, int u)
{
    int a0 = base + 16 * u + ((u >> 1) << 2);   // == base + phys(16u), contiguous run
    float xr[16], xi[16];
#pragma unroll
    for (int v = 0; v < 4; ++v) {
        float4 vr = *(const float4*)(Ar + a0 + 4 * v);
        float4 vi = *(const float4*)(Ai + a0 + 4 * v);
        xr[4 * v] = vr.x; xr[4 * v + 1] = vr.y; xr[4 * v + 2] = vr.z; xr[4 * v + 3] = vr.w;
        xi[4 * v] = vi.x; xi[4 * v + 1] = vi.y; xi[4 * v + 2] = vi.z; xi[4 * v + 3] = vi.w;
    }
    // stage C (D=4): A_m = x[q+4m], twiddle (c,s) of pi*q*r/8
    const float CQ[4][4] = {
        {1.f, 1.f, 1.f, 1.f},
        {1.f, 0.92387953f, 0.70710678f, 0.38268343f},
        {1.f, 0.70710678f, 0.f, -0.70710678f},
        {1.f, 0.38268343f, -0.70710678f, -0.92387953f}};
    const float SQ[4][4] = {
        {0.f, 0.f, 0.f, 0.f},
        {0.f, 0.38268343f, 0.70710678f, 0.92387953f},
        {0.f, 0.70710678f, 1.f, 0.70710678f},
        {0.f, 0.92387953f, 0.70710678f, -0.38268343f}};
#pragma unroll
    for (int q = 0; q < 4; ++q) {
        float t0r = xr[q] + xr[q + 8],       t0i = xi[q] + xi[q + 8];
        float t1r = xr[q] - xr[q + 8],       t1i = xi[q] - xi[q + 8];
        float t2r = xr[q + 4] + xr[q + 12],  t2i = xi[q + 4] + xi[q + 12];
        float t3r = xr[q + 4] - xr[q + 12],  t3i = xi[q + 4] - xi[q + 12];
        xr[q] = t0r + t2r;  xi[q] = t0i + t2i;
        float v1r = t1r + SGN * t3i, v1i = t1i - SGN * t3r;
        float v2r = t0r - t2r,       v2i = t0i - t2i;
        float v3r = t1r - SGN * t3i, v3i = t1i + SGN * t3r;
        twmul<SGN>(v1r, v1i, CQ[q][1], SQ[q][1]);
        twmul<SGN>(v2r, v2i, CQ[q][2], SQ[q][2]);
        twmul<SGN>(v3r, v3i, CQ[q][3], SQ[q][3]);
        xr[q + 4]  = v1r; xi[q + 4]  = v1i;
        xr[q + 8]  = v2r; xi[q + 8]  = v2i;
        xr[q + 12] = v3r; xi[q + 12] = v3i;
    }
    // stage D (D=1): contiguous quads, no twiddle
#pragma unroll
    for (int g = 0; g < 4; ++g) {
        int s0 = 4 * g;
        float t0r = xr[s0] + xr[s0 + 2],     t1r = xr[s0] - xr[s0 + 2];
        float t2r = xr[s0 + 1] + xr[s0 + 3], t3r = xr[s0 + 1] - xr[s0 + 3];
        float t0i = xi[s0] + xi[s0 + 2],     t1i = xi[s0] - xi[s0 + 2];
        float t2i = xi[s0 + 1] + xi[s0 + 3], t3i = xi[s0 + 1] - xi[s0 + 3];
        xr[s0]     = t0r + t2r;
        xr[s0 + 1] = t1r + SGN * t3i;
        xr[s0 + 2] = t0r - t2r;
        xr[s0 + 3] = t1r - SGN * t3i;
        if (!REAL_OUT) {
            xi[s0]     = t0i + t2i;
            xi[s0 + 1] = t1i - SGN * t3r;
            xi[s0 + 2] = t0i - t2i;
            xi[s0 + 3] = t1i + SGN * t3r;
        }
    }
    if (STORE_REV) {
        int q2 = (u >> 2) + ((u & 3) << 2);
#pragma unroll
        for (int s = 0; s < 16; ++s) {
            int dest = q2 + ((s >> 2) << 4) + ((s & 3) << 6);   // rev4(16u+s)
            int a = base + phys(dest);
            Ar[a] = xr[s]; Ai[a] = xi[s];
        }
    } else {
#pragma unroll
        for (int v = 0; v < 4; ++v) {
            *(float4*)(Ar + a0 + 4 * v) = make_float4(xr[4*v], xr[4*v+1], xr[4*v+2], xr[4*v+3]);
            if (!REAL_OUT)
                *(float4*)(Ai + a0 + 4 * v) = make_float4(xi[4*v], xi[4*v+1], xi[4*v+2], xi[4*v+3]);
        }
    }
}

// Wc4[i][jc][f] = float4(Hc[f][i][2jc].re,.im, Hc[f][i][2jc+1].re,.im),
// f = 0..128 (pad 132), Hc = conj(FFT_256(W[i,j,:])). 270 KB in d_ws.
__global__ __launch_bounds__(256) void wfft_kernel(const float* __restrict__ W,
                                                   float* __restrict__ Wc4)
{
    __shared__ float wblk[256];
    __shared__ float tabc[256], tabs[256];
    int t   = threadIdx.x;                 // t = frequency f
    int blk = blockIdx.x;                  // blk = i*16 + j
    wblk[t] = W[blk * 256 + t];
    float s, c;
    __sincosf((float)t * (TWO_PI / 256.f), &s, &c);
    tabc[t] = c; tabs[t] = s;
    __syncthreads();
    if (t <= 128) {
        float ar = 0.f, ai = 0.f;
        for (int cc = 0; cc < 256; ++cc) {
            int idx = (t * cc) & 255;
            float wv = wblk[cc];
            ar = fmaf(wv, tabc[idx], ar);
            ai = fmaf(wv, tabs[idx], ai);
        }
        int i = blk >> 4, j = blk & 15;
        int flat = ((i * 8 + (j >> 1)) * 132 + t) * 4 + ((j & 1) << 1);
        Wc4[flat]     = ar;
        Wc4[flat + 1] = ai;
    }
}

__global__ __launch_bounds__(256) void bc_kernel(const float* __restrict__ x,
                                                 const float* __restrict__ d,
                                                 const float* __restrict__ bias,
                                                 const float* __restrict__ Wc4,
                                                 float* __restrict__ out)
{
    __shared__ float Ar[16 * RS], Ai[16 * RS];
    int t = threadIdx.x;
    int b = blockIdx.x;
    int w = t >> 6, l = t & 63;
    int u = t & 15;
    int base = (t >> 4) * RS;              // region = 4w + (l>>4), wave-owned

    // ---- load: wave w loads its own regions 4w..4w+3 (coalesced float4)
    const float4* x4 = (const float4*)(x + (size_t)b * 4096);
    const float4* d4 = (const float4*)d;
#pragma unroll
    for (int it = 0; it < 4; ++it) {
        int idx = 256 * w + 64 * it + l;
        float4 xv = x4[idx], dv = d4[idx];
        int a = (4 * w + it) * RS + 4 * l + ((l >> 3) << 2);   // phys(4l)
        *(float4*)(Ar + a) = make_float4(xv.x * dv.x, xv.y * dv.y, xv.z * dv.z, xv.w * dv.w);
    }
    // no barrier: regions are wave-private, DS ops in-order within a wave

    pair1<1, true>(Ar, Ai, base, u);
    pair2<1, true, false>(Ar, Ai, base, u);   // scatter -> natural-order spectrum
    __syncthreads();                           // BAR 1: matmul reads cross-wave

    // ---- frequency matmul: 2 threads per f (i 0..7 / 8..15), conj symmetry
    {
        int f  = (t <= 128) ? t : (t - 128);
        int pf = phys(f);
        float vr[16], vi[16];
#pragma unroll
        for (int j = 0; j < 16; ++j) { vr[j] = Ar[j * RS + pf]; vi[j] = Ai[j * RS + pf]; }
        __syncthreads();                       // BAR 2: all reads before writes
        int i0 = (t <= 128) ? 0 : 8;
        const float4* wb = (const float4*)Wc4;
#pragma unroll 1
        for (int pass = 0; pass < 2; ++pass) {
            if (pass == 1 && !(t == 0 || t == 128)) break;
            int ib = (pass == 0) ? i0 : 8;
#pragma unroll
            for (int io = 0; io < 8; ++io) {
                int i = ib + io;
                float yr = 0.f, yi = 0.f;
#pragma unroll
                for (int jc = 0; jc < 8; ++jc) {
                    float4 wv = wb[(i * 8 + jc) * 132 + f];
                    int j0 = 2 * jc;
                    yr = fmaf(vr[j0], wv.x, yr); yr = fmaf(-vi[j0], wv.y, yr);
                    yi = fmaf(vr[j0], wv.y, yi); yi = fmaf(vi[j0], wv.x, yi);
                    yr = fmaf(vr[j0+1], wv.z, yr); yr = fmaf(-vi[j0+1], wv.w, yr);
                    yi = fmaf(vr[j0+1], wv.w, yi); yi = fmaf(vi[j0+1], wv.z, yi);
                }
                Ar[i * RS + pf] = yr;
                Ai[i * RS + pf] = yi;
                if (f >= 1 && f <= 127) {      // conjugate symmetry fills f>128
                    int pc = phys(256 - f);
                    Ar[i * RS + pc] = yr;
                    Ai[i * RS + pc] = -yi;
                }
            }
        }
    }
    __syncthreads();                           // BAR 3

    pair1<-1, false>(Ar, Ai, base, u);
    pair2<-1, false, true>(Ar, Ai, base, u);   // real-only, contiguous store
    // no barrier: gather below reads own-wave regions only

    // ---- store: gather rev4 positions (b32, 2-way), coalesced float4 global
    const float4* b4 = (const float4*)bias;
    float* op = out + (size_t)b * 4096;
    int dbase = ((l >> 4) & 3) + (((l >> 2) & 3) << 2) + ((l & 3) << 4);
#pragma unroll
    for (int it = 0; it < 4; ++it) {
        int idx = 256 * w + 64 * it + l;
        int rb  = (4 * w + it) * RS;
        float vv[4];
#pragma unroll
        for (int e = 0; e < 4; ++e) {
            int dest = dbase + (e << 6);       // rev4(4l+e)
            vv[e] = Ar[rb + phys(dest)];
        }
        float4 bv = b4[idx];
        float4 ov;
        ov.x = vv[0] * (1.f / 256.f) + bv.x;
        ov.y = vv[1] * (1.f / 256.f) + bv.y;
        ov.z = vv[2] * (1.f / 256.f) + bv.z;
        ov.w = vv[3] * (1.f / 256.f) + bv.w;
        ((float4*)op)[idx] = ov;
    }
}

extern "C" void kernel_launch(void* const* d_in, const int* in_sizes, int n_in,
                              void* d_out, int out_size, void* d_ws, size_t ws_size,
                              hipStream_t stream)
{
    const float* x    = (const float*)d_in[0];   // (8192, 4096)
    const float* W    = (const float*)d_in[1];   // (16, 16, 256)
    const float* d    = (const float*)d_in[2];   // (4096,)
    const float* bias = (const float*)d_in[3];   // (4096,)
    float* out = (float*)d_out;
    float* Wc4 = (float*)d_ws;                   // [16][8][132] float4 = 270 KB

    wfft_kernel<<<256, 256, 0, stream>>>(W, Wc4);
    bc_kernel<<<8192, 256, 0, stream>>>(x, d, bias, Wc4, out);
}